// Round 1
// baseline (220.281 us; speedup 1.0000x reference)
//
#include <hip/hip_runtime.h>
#include <hip/hip_bf16.h>

#define NPIX 6400
#define LOG2E 1.44269504088896340736f

typedef _Float16 half_t;
typedef _Float16 half4 __attribute__((ext_vector_type(4)));
typedef float float4x __attribute__((ext_vector_type(4)));

// ---------------- projections ----------------

__global__ __launch_bounds__(256) void qk_proj_kernel(
    const float* __restrict__ a, const float* __restrict__ b, const float* __restrict__ c,
    const float* __restrict__ wq_ab, const float* __restrict__ bq_ab,
    const float* __restrict__ wk_ab, const float* __restrict__ bk_ab,
    const float* __restrict__ wq_bc, const float* __restrict__ bq_bc,
    const float* __restrict__ wk_bc, const float* __restrict__ bk_bc,
    half_t* __restrict__ qp, half_t* __restrict__ kp)
{
    int tid = blockIdx.x * 256 + threadIdx.x;      // 0..12799  (2 * 6400)
    int bz = tid / NPIX, n = tid % NPIX;
    const float* A = a + bz * 64 * NPIX + n;
    const float* B = b + bz * 64 * NPIX + n;
    const float* C = c + bz * 64 * NPIX + n;
    float qab[4] = {0,0,0,0}, kab[4] = {0,0,0,0}, qbc[4] = {0,0,0,0}, kbc[4] = {0,0,0,0};
    for (int ch = 0; ch < 64; ++ch) {
        float av = A[ch * NPIX], bv = B[ch * NPIX], cv = C[ch * NPIX];
#pragma unroll
        for (int d = 0; d < 4; ++d) {
            qab[d] += wq_ab[d * 64 + ch] * av;
            kab[d] += wk_ab[d * 64 + ch] * bv;
            qbc[d] += wq_bc[d * 64 + ch] * cv;
            kbc[d] += wk_bc[d * 64 + ch] * bv;
        }
    }
    // layouts: qp/kp [bz][branch][n][4] fp16; log2e folded into q so scores are in exp2 domain
    half_t* q0 = qp + ((bz * 2 + 0) * NPIX + n) * 4;
    half_t* q1 = qp + ((bz * 2 + 1) * NPIX + n) * 4;
    half_t* k0 = kp + ((bz * 2 + 0) * NPIX + n) * 4;
    half_t* k1 = kp + ((bz * 2 + 1) * NPIX + n) * 4;
#pragma unroll
    for (int d = 0; d < 4; ++d) {
        q0[d] = (half_t)((qab[d] + bq_ab[d]) * LOG2E);
        q1[d] = (half_t)((qbc[d] + bq_bc[d]) * LOG2E);
        k0[d] = (half_t)(kab[d] + bk_ab[d]);
        k1[d] = (half_t)(kbc[d] + bk_bc[d]);
    }
}

__global__ __launch_bounds__(256) void v_proj_kernel(
    const float* __restrict__ b, const float* __restrict__ wv,
    const float* __restrict__ bvb, half_t* __restrict__ vp)
{
    int tid = blockIdx.x * 256 + threadIdx.x;      // 0..819199 = [bz][c][n]
    int bz = tid / (64 * NPIX);
    int c  = (tid / NPIX) & 63;
    int n  = tid % NPIX;
    const float* B = b + bz * 64 * NPIX + n;
    float acc = bvb[c];
    for (int ch = 0; ch < 64; ++ch) acc += wv[c * 64 + ch] * B[ch * NPIX];
    vp[tid] = (half_t)acc;                          // vp [bz][c][n] fp16
}

// ---------------- fused attention (flash, no-max softmax, split-K) ----------------
// grid = 800: (khalf 2) x (bz 2) x (branch 2) x (qchunk 100); 4 waves/block, 16 queries/wave.
// Scores: mfma16x16x16f16(A=K,B=Q) -> lane holds S[m=4g+r][q=lane&15]  (g = lane>>4)
// which is exactly the B-fragment layout for the PV mfma -> P stays in-lane.

__global__ __launch_bounds__(256) void attn_kernel(
    const half_t* __restrict__ qp, const half_t* __restrict__ kp,
    const half_t* __restrict__ vp, float* __restrict__ num, float* __restrict__ lsum)
{
    int idx = blockIdx.x;                // 0..799
    int qc = idx % 100;
    int br = (idx / 100) & 1;
    int bz = (idx / 200) & 1;
    int kh = idx / 400;                  // key-half (split-K)
    int tid = threadIdx.x;
    int lane = tid & 63, w = tid >> 6;
    int g = lane >> 4, qi = lane & 15;
    int qbase = qc * 64 + w * 16;

    const half_t* Q = qp + ((bz * 2 + br) * NPIX + qbase) * 4;
    const half_t* K = kp + (bz * 2 + br) * NPIX * 4;
    const half_t* V = vp + bz * 64 * NPIX;

    half4 qf = {(half_t)0, (half_t)0, (half_t)0, (half_t)0};
    if (lane < 16) qf = *(const half4*)(Q + lane * 4);   // B-frag: B[d=j][q=lane]

    float4x accs[4] = {{0,0,0,0},{0,0,0,0},{0,0,0,0},{0,0,0,0}};
    float lrun = 0.f;

    // V tile: 64 keys x 64 ch fp16, row stride 144 B (pad) -> bank-balanced b128 writes / b64 reads
    __shared__ char lds[64 * 144];

    for (int chn = 0; chn < 50; ++chn) {
        int m0 = (kh * 50 + chn) * 64;
        __syncthreads();
        // stage V chunk: 512 x 16B segments, 2 per thread
#pragma unroll
        for (int si = 0; si < 2; ++si) {
            int s = tid + si * 256;
            int cc = s >> 3, so = s & 7;
            float4x seg = *(const float4x*)(V + cc * NPIX + m0 + so * 8);
            *(float4x*)(lds + cc * 144 + so * 16) = seg;
        }
        __syncthreads();
#pragma unroll
        for (int t = 0; t < 4; ++t) {
            int mt = m0 + t * 16;
            half4 kf = {(half_t)0, (half_t)0, (half_t)0, (half_t)0};
            if (lane < 16) kf = *(const half4*)(K + (mt + lane) * 4);  // A-frag: A[m=lane][d=j]
            float4x zero = {0.f, 0.f, 0.f, 0.f};
            float4x sc = __builtin_amdgcn_mfma_f32_16x16x16f16(kf, qf, zero, 0, 0, 0);
            // softmax without max-subtraction: |s*log2e| < ~3, exp2 always in range
            float p0 = exp2f(sc[0]), p1 = exp2f(sc[1]), p2 = exp2f(sc[2]), p3 = exp2f(sc[3]);
            lrun += (p0 + p1) + (p2 + p3);
            half4 pf = {(half_t)p0, (half_t)p1, (half_t)p2, (half_t)p3};
            const char* lrow = lds + t * 32 + g * 8;
#pragma unroll
            for (int cb = 0; cb < 4; ++cb) {
                half4 vf = *(const half4*)(lrow + (cb * 16 + qi) * 144); // A[c=qi][m=4g+j]
                accs[cb] = __builtin_amdgcn_mfma_f32_16x16x16f16(vf, pf, accs[cb], 0, 0, 0);
            }
        }
    }

    // denominator: sum partial l over the 4 lane-groups (same q)
    lrun += __shfl_xor(lrun, 16, 64);
    lrun += __shfl_xor(lrun, 32, 64);
    int q = qbase + qi;
    if (g == 0) atomicAdd(&lsum[(bz * 2 + br) * NPIX + q], lrun);

    // numerator: D layout col=q=lane&15, row(c within block)=4g+r
    float* numb = num + (bz * 2 + br) * 64 * NPIX;
#pragma unroll
    for (int cb = 0; cb < 4; ++cb)
#pragma unroll
        for (int r = 0; r < 4; ++r)
            atomicAdd(&numb[(cb * 16 + 4 * g + r) * NPIX + q], accs[cb][r]);
}

__global__ __launch_bounds__(256) void norm_kernel(
    const float* __restrict__ num, const float* __restrict__ lsum, float* __restrict__ out)
{
    int tid = blockIdx.x * 256 + threadIdx.x;   // 0..819199 = [bz][c][n]
    int bz = tid / (64 * NPIX);
    int c  = (tid / NPIX) & 63;
    int n  = tid % NPIX;
    float lA = lsum[(bz * 2 + 0) * NPIX + n];
    float lC = lsum[(bz * 2 + 1) * NPIX + n];
    float vA = num[((bz * 2 + 0) * 64 + c) * NPIX + n];
    float vC = num[((bz * 2 + 1) * 64 + c) * NPIX + n];
    out[tid] = 0.5f * (vA / lA + vC / lC);
}

extern "C" void kernel_launch(void* const* d_in, const int* in_sizes, int n_in,
                              void* d_out, int out_size, void* d_ws, size_t ws_size,
                              hipStream_t stream) {
    (void)in_sizes; (void)n_in; (void)out_size; (void)ws_size;
    const float* a     = (const float*)d_in[0];
    const float* b     = (const float*)d_in[1];
    const float* c     = (const float*)d_in[2];
    const float* wq_ab = (const float*)d_in[3];
    const float* bq_ab = (const float*)d_in[4];
    const float* wk_ab = (const float*)d_in[5];
    const float* bk_ab = (const float*)d_in[6];
    const float* wq_bc = (const float*)d_in[7];
    const float* bq_bc = (const float*)d_in[8];
    const float* wk_bc = (const float*)d_in[9];
    const float* bk_bc = (const float*)d_in[10];
    const float* wv    = (const float*)d_in[11];
    const float* bv    = (const float*)d_in[12];
    float* out = (float*)d_out;

    // workspace layout (bytes): qp 204800 | kp 204800 | vp 1638400 | num 6553600 | lsum 102400
    half_t* qp = (half_t*)d_ws;
    half_t* kp = qp + 2 * 2 * NPIX * 4;
    half_t* vp = kp + 2 * 2 * NPIX * 4;
    float* num  = (float*)(vp + 2 * 64 * NPIX);
    float* lsum = num + 2 * 2 * 64 * NPIX;

    hipMemsetAsync(num, 0, (size_t)(2 * 2 * 64 * NPIX + 2 * 2 * NPIX) * sizeof(float), stream);

    qk_proj_kernel<<<50, 256, 0, stream>>>(a, b, c, wq_ab, bq_ab, wk_ab, bk_ab,
                                           wq_bc, bq_bc, wk_bc, bk_bc, qp, kp);
    v_proj_kernel<<<3200, 256, 0, stream>>>(b, wv, bv, vp);
    attn_kernel<<<800, 256, 0, stream>>>(qp, kp, vp, num, lsum);
    norm_kernel<<<3200, 256, 0, stream>>>(num, lsum, out);
}

// Round 9
// 213.369 us; speedup vs baseline: 1.0324x; 1.0324x over previous
//
#include <hip/hip_runtime.h>
#include <hip/hip_bf16.h>

#define NPIX 6400
#define LOG2E 1.44269504088896340736f
#define KH 4          // split-K ways
#define KEYS 1600     // keys per split = NPIX/KH
#define NCH 25        // 64-key chunks per block = KEYS/64
#define QF 2          // query fragments (16q each) per wave

typedef _Float16 half_t;
typedef _Float16 half4 __attribute__((ext_vector_type(4)));
typedef float float4x __attribute__((ext_vector_type(4)));

// ---------------- projections ----------------

// one thread per (bz, n, d): 2*6400*4 = 51200 threads
__global__ __launch_bounds__(256) void qk_proj_kernel(
    const float* __restrict__ a, const float* __restrict__ b, const float* __restrict__ c,
    const float* __restrict__ wq_ab, const float* __restrict__ bq_ab,
    const float* __restrict__ wk_ab, const float* __restrict__ bk_ab,
    const float* __restrict__ wq_bc, const float* __restrict__ bq_bc,
    const float* __restrict__ wk_bc, const float* __restrict__ bk_bc,
    half_t* __restrict__ qp, half_t* __restrict__ kp)
{
    int tid = blockIdx.x * 256 + threadIdx.x;
    int d = tid & 3;
    int n = (tid >> 2) % NPIX;
    int bz = (tid >> 2) / NPIX;
    const float* A = a + bz * 64 * NPIX + n;
    const float* B = b + bz * 64 * NPIX + n;
    const float* C = c + bz * 64 * NPIX + n;
    float qab = 0.f, kab = 0.f, qbc = 0.f, kbc = 0.f;
#pragma unroll 4
    for (int ch = 0; ch < 64; ++ch) {
        float av = A[ch * NPIX], bv = B[ch * NPIX], cv = C[ch * NPIX];
        qab += wq_ab[d * 64 + ch] * av;
        kab += wk_ab[d * 64 + ch] * bv;
        qbc += wq_bc[d * 64 + ch] * cv;
        kbc += wk_bc[d * 64 + ch] * bv;
    }
    // qp/kp layout: [bz][branch][n][4] fp16; log2e folded into q
    qp[((bz * 2 + 0) * NPIX + n) * 4 + d] = (half_t)((qab + bq_ab[d]) * LOG2E);
    qp[((bz * 2 + 1) * NPIX + n) * 4 + d] = (half_t)((qbc + bq_bc[d]) * LOG2E);
    kp[((bz * 2 + 0) * NPIX + n) * 4 + d] = (half_t)(kab + bk_ab[d]);
    kp[((bz * 2 + 1) * NPIX + n) * 4 + d] = (half_t)(kbc + bk_bc[d]);
}

// one thread per (bz, c, n4): 2*64*1600 threads, float4 loads
__global__ __launch_bounds__(256) void v_proj_kernel(
    const float* __restrict__ b, const float* __restrict__ wv,
    const float* __restrict__ bvb, half_t* __restrict__ vp)
{
    int tid = blockIdx.x * 256 + threadIdx.x;
    int n4 = tid % 1600;
    int c  = (tid / 1600) & 63;
    int bz = tid / (1600 * 64);
    const float* B = b + bz * 64 * NPIX + n4 * 4;
    float bias = bvb[c];
    float4x acc = {bias, bias, bias, bias};
    for (int ch = 0; ch < 64; ++ch) {
        float4x bv = *(const float4x*)(B + ch * NPIX);
        float wcc = wv[c * 64 + ch];
        acc += wcc * bv;
    }
    half4 hv = {(half_t)acc[0], (half_t)acc[1], (half_t)acc[2], (half_t)acc[3]};
    *(half4*)(vp + (bz * 64 + c) * NPIX + n4 * 4) = hv;   // vp [bz][c][n] fp16
}

// ---------------- fused attention (flash, no-max softmax, split-K, pipelined) ----
// grid = 800 (XCD-swizzled): (kh 4) x (bz 2) x (branch 2) x (qchunk 50); 4 waves,
// each wave owns 32 queries (2 fragments). Per 64-key chunk: V staged in LDS
// (double-buffered), K fragments + V segments prefetched one chunk ahead.
// Scores: mfma16x16x16f16(A=K,B=Q) -> lane holds S[m=4g+r][q] == PV B-frag layout.

__global__ __launch_bounds__(256) void attn_kernel(
    const half_t* __restrict__ qp, const half_t* __restrict__ kp,
    const half_t* __restrict__ vp, float* __restrict__ num, float* __restrict__ lsum)
{
    int bid = blockIdx.x;
    int swz = (bid & 7) * 100 + (bid >> 3);   // XCD-aware, bijective (800 % 8 == 0)
    int qc = swz % 50;
    int br = (swz / 50) & 1;
    int bz = (swz / 100) & 1;
    int kh = swz / 200;

    int tid = threadIdx.x;
    int lane = tid & 63, w = tid >> 6;
    int g = lane >> 4, qi = lane & 15;
    int qbase = qc * 128 + w * 32;

    const half_t* Q = qp + ((bz * 2 + br) * NPIX + qbase) * 4;
    const half_t* K = kp + ((bz * 2 + br) * NPIX + kh * KEYS) * 4;
    const half_t* V = vp + bz * 64 * NPIX + kh * KEYS;

    half4 hz = {(half_t)0, (half_t)0, (half_t)0, (half_t)0};
    half4 qf[QF];
#pragma unroll
    for (int i = 0; i < QF; ++i)
        qf[i] = (lane < 16) ? *(const half4*)(Q + (i * 16 + lane) * 4) : hz;

    float4x accs[QF][4] = {{{0,0,0,0},{0,0,0,0},{0,0,0,0},{0,0,0,0}},
                           {{0,0,0,0},{0,0,0,0},{0,0,0,0},{0,0,0,0}}};
    float lrun[QF] = {0.f, 0.f};

    // V tile: 64 keys x 64 ch fp16, row stride 144B (bank-balanced), double-buffered
    __shared__ char lds[2][64 * 144];
    int cc0 = tid >> 3, so0 = tid & 7;   // seg 0: channels 0..31
    int cc1 = cc0 + 32;                  // seg 1: channels 32..63

    // prologue: stage chunk 0
    float4x ga = *(const float4x*)(V + cc0 * NPIX + so0 * 8);
    float4x gb = *(const float4x*)(V + cc1 * NPIX + so0 * 8);
    half4 kc[4];
#pragma unroll
    for (int t = 0; t < 4; ++t)
        kc[t] = (lane < 16) ? *(const half4*)(K + (t * 16 + lane) * 4) : hz;
    *(float4x*)(lds[0] + cc0 * 144 + so0 * 16) = ga;
    *(float4x*)(lds[0] + cc1 * 144 + so0 * 16) = gb;
    __syncthreads();

    int cur = 0;
    for (int chn = 0; chn < NCH; ++chn) {
        bool more = (chn + 1 < NCH);
        float4x gna, gnb;
        half4 kn[4];
        if (more) {   // issue next-chunk loads early; consumed after compute
            int m0n = (chn + 1) * 64;
            gna = *(const float4x*)(V + cc0 * NPIX + m0n + so0 * 8);
            gnb = *(const float4x*)(V + cc1 * NPIX + m0n + so0 * 8);
#pragma unroll
            for (int t = 0; t < 4; ++t)
                kn[t] = (lane < 16) ? *(const half4*)(K + (m0n + t * 16 + lane) * 4) : hz;
        }
        const char* lb = lds[cur];
#pragma unroll
        for (int t = 0; t < 4; ++t) {
            half4 vf[4];
#pragma unroll
            for (int cb = 0; cb < 4; ++cb)
                vf[cb] = *(const half4*)(lb + (cb * 16 + qi) * 144 + t * 32 + g * 8);
#pragma unroll
            for (int i = 0; i < QF; ++i) {
                float4x zero = {0.f, 0.f, 0.f, 0.f};
                float4x sc = __builtin_amdgcn_mfma_f32_16x16x16f16(kc[t], qf[i], zero, 0, 0, 0);
                float p0 = exp2f(sc[0]), p1 = exp2f(sc[1]), p2 = exp2f(sc[2]), p3 = exp2f(sc[3]);
                lrun[i] += (p0 + p1) + (p2 + p3);
                half4 pf = {(half_t)p0, (half_t)p1, (half_t)p2, (half_t)p3};
#pragma unroll
                for (int cb = 0; cb < 4; ++cb)
                    accs[i][cb] = __builtin_amdgcn_mfma_f32_16x16x16f16(vf[cb], pf, accs[i][cb], 0, 0, 0);
            }
        }
        if (more) {
            *(float4x*)(lds[cur ^ 1] + cc0 * 144 + so0 * 16) = gna;
            *(float4x*)(lds[cur ^ 1] + cc1 * 144 + so0 * 16) = gnb;
#pragma unroll
            for (int t = 0; t < 4; ++t) kc[t] = kn[t];
        }
        __syncthreads();
        cur ^= 1;
    }

    float* numb = num + (bz * 2 + br) * 64 * NPIX;
#pragma unroll
    for (int i = 0; i < QF; ++i) {
        float l = lrun[i];
        l += __shfl_xor(l, 16, 64);
        l += __shfl_xor(l, 32, 64);
        int q = qbase + i * 16 + qi;
        if (g == 0) atomicAdd(&lsum[(bz * 2 + br) * NPIX + q], l);
#pragma unroll
        for (int cb = 0; cb < 4; ++cb)
#pragma unroll
            for (int r = 0; r < 4; ++r)
                atomicAdd(&numb[(cb * 16 + 4 * g + r) * NPIX + q], accs[i][cb][r]);
    }
}

// one thread per (bz, c, n4), float4
__global__ __launch_bounds__(256) void norm_kernel(
    const float* __restrict__ num, const float* __restrict__ lsum, float* __restrict__ out)
{
    int tid = blockIdx.x * 256 + threadIdx.x;
    int n4 = tid % 1600;
    int c  = (tid / 1600) & 63;
    int bz = tid / (1600 * 64);
    float4x lA = *(const float4x*)(lsum + (bz * 2 + 0) * NPIX + n4 * 4);
    float4x lC = *(const float4x*)(lsum + (bz * 2 + 1) * NPIX + n4 * 4);
    float4x vA = *(const float4x*)(num + ((bz * 2 + 0) * 64 + c) * NPIX + n4 * 4);
    float4x vC = *(const float4x*)(num + ((bz * 2 + 1) * 64 + c) * NPIX + n4 * 4);
    float4x r;
#pragma unroll
    for (int j = 0; j < 4; ++j)
        r[j] = 0.5f * (vA[j] * __builtin_amdgcn_rcpf(lA[j]) +
                       vC[j] * __builtin_amdgcn_rcpf(lC[j]));
    *(float4x*)(out + (bz * 64 + c) * NPIX + n4 * 4) = r;
}

extern "C" void kernel_launch(void* const* d_in, const int* in_sizes, int n_in,
                              void* d_out, int out_size, void* d_ws, size_t ws_size,
                              hipStream_t stream) {
    (void)in_sizes; (void)n_in; (void)out_size; (void)ws_size;
    const float* a     = (const float*)d_in[0];
    const float* b     = (const float*)d_in[1];
    const float* c     = (const float*)d_in[2];
    const float* wq_ab = (const float*)d_in[3];
    const float* bq_ab = (const float*)d_in[4];
    const float* wk_ab = (const float*)d_in[5];
    const float* bk_ab = (const float*)d_in[6];
    const float* wq_bc = (const float*)d_in[7];
    const float* bq_bc = (const float*)d_in[8];
    const float* wk_bc = (const float*)d_in[9];
    const float* bk_bc = (const float*)d_in[10];
    const float* wv    = (const float*)d_in[11];
    const float* bv    = (const float*)d_in[12];
    float* out = (float*)d_out;

    // workspace: qp | kp | vp | num | lsum
    half_t* qp = (half_t*)d_ws;
    half_t* kp = qp + 2 * 2 * NPIX * 4;
    half_t* vp = kp + 2 * 2 * NPIX * 4;
    float* num  = (float*)(vp + 2 * 64 * NPIX);
    float* lsum = num + 2 * 2 * 64 * NPIX;

    hipMemsetAsync(num, 0, (size_t)(2 * 2 * 64 * NPIX + 2 * 2 * NPIX) * sizeof(float), stream);

    qk_proj_kernel<<<200, 256, 0, stream>>>(a, b, c, wq_ab, bq_ab, wk_ab, bk_ab,
                                            wq_bc, bq_bc, wk_bc, bk_bc, qp, kp);
    v_proj_kernel<<<800, 256, 0, stream>>>(b, wv, bv, vp);
    attn_kernel<<<800, 256, 0, stream>>>(qp, kp, vp, num, lsum);
    norm_kernel<<<800, 256, 0, stream>>>(num, lsum, out);
}

// Round 10
// 199.522 us; speedup vs baseline: 1.1040x; 1.0694x over previous
//
#include <hip/hip_runtime.h>
#include <hip/hip_bf16.h>

#define NPIX 6400
#define LOG2E 1.44269504088896340736f
#define KH 5          // split-K ways -> grid 1000 = 3*256+232 (2% tail waste)
#define KEYS 1280     // keys per split
#define NCH 20        // 64-key chunks per block
#define QF 2          // query fragments (16q each) per wave
#define VSTRIDE 136   // V LDS row stride bytes (34 words: 2-way banks for b64 r/w)

typedef _Float16 half_t;
typedef _Float16 half4 __attribute__((ext_vector_type(4)));
typedef float float4x __attribute__((ext_vector_type(4)));
typedef unsigned long long u64;

// ---------------- fused projections ----------------
// blocks 0..399:  v_proj, thread per (bz, c in 0..31, n4); computes c and c+32
// blocks 400..599: qk_proj, thread per (bz, n, d)
__global__ __launch_bounds__(256) void proj_kernel(
    const float* __restrict__ a, const float* __restrict__ b, const float* __restrict__ c,
    const float* __restrict__ wq_ab, const float* __restrict__ bq_ab,
    const float* __restrict__ wk_ab, const float* __restrict__ bk_ab,
    const float* __restrict__ wq_bc, const float* __restrict__ bq_bc,
    const float* __restrict__ wk_bc, const float* __restrict__ bk_bc,
    const float* __restrict__ wv, const float* __restrict__ bvb,
    half_t* __restrict__ qp, half_t* __restrict__ kp, half_t* __restrict__ vp)
{
    int bid = blockIdx.x;
    if (bid < 400) {
        int tid = bid * 256 + threadIdx.x;       // 0..102399
        int n4 = tid % 1600;
        int cc = (tid / 1600) & 31;
        int bz = tid / (1600 * 32);
        const float* B = b + bz * 64 * NPIX + n4 * 4;
        float b0 = bvb[cc], b1 = bvb[cc + 32];
        float4x acc0 = {b0, b0, b0, b0}, acc1 = {b1, b1, b1, b1};
        for (int ch = 0; ch < 64; ++ch) {
            float4x bv = *(const float4x*)(B + ch * NPIX);
            acc0 += wv[cc * 64 + ch] * bv;
            acc1 += wv[(cc + 32) * 64 + ch] * bv;
        }
        half4 h0 = {(half_t)acc0[0], (half_t)acc0[1], (half_t)acc0[2], (half_t)acc0[3]};
        half4 h1 = {(half_t)acc1[0], (half_t)acc1[1], (half_t)acc1[2], (half_t)acc1[3]};
        *(half4*)(vp + (bz * 64 + cc) * NPIX + n4 * 4) = h0;
        *(half4*)(vp + (bz * 64 + cc + 32) * NPIX + n4 * 4) = h1;
    } else {
        int tid = (bid - 400) * 256 + threadIdx.x;   // 0..51199
        int d = tid & 3;
        int n = (tid >> 2) % NPIX;
        int bz = (tid >> 2) / NPIX;
        const float* A = a + bz * 64 * NPIX + n;
        const float* B = b + bz * 64 * NPIX + n;
        const float* C = c + bz * 64 * NPIX + n;
        float qab = 0.f, kab = 0.f, qbc = 0.f, kbc = 0.f;
#pragma unroll 4
        for (int ch = 0; ch < 64; ++ch) {
            float av = A[ch * NPIX], bv = B[ch * NPIX], cv = C[ch * NPIX];
            qab += wq_ab[d * 64 + ch] * av;
            kab += wk_ab[d * 64 + ch] * bv;
            qbc += wq_bc[d * 64 + ch] * cv;
            kbc += wk_bc[d * 64 + ch] * bv;
        }
        // qp/kp layout: [bz][branch][n][4] fp16; log2e folded into q
        qp[((bz * 2 + 0) * NPIX + n) * 4 + d] = (half_t)((qab + bq_ab[d]) * LOG2E);
        qp[((bz * 2 + 1) * NPIX + n) * 4 + d] = (half_t)((qbc + bq_bc[d]) * LOG2E);
        kp[((bz * 2 + 0) * NPIX + n) * 4 + d] = (half_t)(kab + bk_ab[d]);
        kp[((bz * 2 + 1) * NPIX + n) * 4 + d] = (half_t)(kbc + bk_bc[d]);
    }
}

// ---------------- fused attention (flash, no-max softmax, split-K, pipelined) ----
// grid = 1000 (XCD-swizzled): (kh 5) x (bz 2) x (branch 2) x (qchunk 50); 4 waves,
// each wave owns 32 queries (2 fragments). V tile staged in LDS double-buffered at
// 136B row stride via b64 writes (both write and read ~2-way bank-free).
// Scores: mfma16x16x16f16(A=K,B=Q) -> lane holds S[m=4g+r][q] == PV B-frag layout.
__global__ __launch_bounds__(256) void attn_kernel(
    const half_t* __restrict__ qp, const half_t* __restrict__ kp,
    const half_t* __restrict__ vp, float* __restrict__ num, float* __restrict__ lsum)
{
    int bid = blockIdx.x;
    int swz = (bid & 7) * 125 + (bid >> 3);   // bijective (1000 = 8*125)
    int qc = swz % 50;
    int br = (swz / 50) & 1;
    int bz = (swz / 100) & 1;
    int kh = swz / 200;                        // 0..4

    int tid = threadIdx.x;
    int lane = tid & 63, w = tid >> 6;
    int g = lane >> 4, qi = lane & 15;
    int qbase = qc * 128 + w * 32;

    const half_t* Q = qp + ((bz * 2 + br) * NPIX + qbase) * 4;
    const half_t* K = kp + ((bz * 2 + br) * NPIX + kh * KEYS) * 4;
    const half_t* V = vp + bz * 64 * NPIX + kh * KEYS;

    half4 hz = {(half_t)0, (half_t)0, (half_t)0, (half_t)0};
    half4 qf[QF];
#pragma unroll
    for (int i = 0; i < QF; ++i)
        qf[i] = (lane < 16) ? *(const half4*)(Q + (i * 16 + lane) * 4) : hz;

    float4x accs[QF][4] = {{{0,0,0,0},{0,0,0,0},{0,0,0,0},{0,0,0,0}},
                           {{0,0,0,0},{0,0,0,0},{0,0,0,0},{0,0,0,0}}};
    float lrun[QF] = {0.f, 0.f};

    __shared__ char lds[2][64 * VSTRIDE];

    // prologue: stage chunk 0 (4 b64 slots/thread: idx=p*256+tid -> row=idx>>4, w4=idx&15)
    u64 vpre[4];
#pragma unroll
    for (int p = 0; p < 4; ++p) {
        int idx = p * 256 + tid; int row = idx >> 4, w4 = idx & 15;
        vpre[p] = *(const u64*)(V + row * NPIX + w4 * 4);
    }
    half4 kc[4];
#pragma unroll
    for (int t = 0; t < 4; ++t)
        kc[t] = (lane < 16) ? *(const half4*)(K + (t * 16 + lane) * 4) : hz;
#pragma unroll
    for (int p = 0; p < 4; ++p) {
        int idx = p * 256 + tid; int row = idx >> 4, w4 = idx & 15;
        *(u64*)(lds[0] + row * VSTRIDE + w4 * 8) = vpre[p];
    }
    __syncthreads();

    int cur = 0;
    for (int chn = 0; chn < NCH; ++chn) {
        bool more = (chn + 1 < NCH);
        u64 vn[4];
        half4 kn[4];
        if (more) {   // issue next-chunk loads early; consumed after compute
            int m0n = (chn + 1) * 64;
#pragma unroll
            for (int p = 0; p < 4; ++p) {
                int idx = p * 256 + tid; int row = idx >> 4, w4 = idx & 15;
                vn[p] = *(const u64*)(V + row * NPIX + m0n + w4 * 4);
            }
#pragma unroll
            for (int t = 0; t < 4; ++t)
                kn[t] = (lane < 16) ? *(const half4*)(K + (m0n + t * 16 + lane) * 4) : hz;
        }
        const char* lb = lds[cur];
#pragma unroll
        for (int t = 0; t < 4; ++t) {
            half4 vf[4];
#pragma unroll
            for (int cb = 0; cb < 4; ++cb)
                vf[cb] = *(const half4*)(lb + (cb * 16 + qi) * VSTRIDE + t * 32 + g * 8);
#pragma unroll
            for (int i = 0; i < QF; ++i) {
                float4x zero = {0.f, 0.f, 0.f, 0.f};
                float4x sc = __builtin_amdgcn_mfma_f32_16x16x16f16(kc[t], qf[i], zero, 0, 0, 0);
                // no-max softmax: |s*log2e| < ~3, exp2 always in range
                float p0 = exp2f(sc[0]), p1 = exp2f(sc[1]), p2 = exp2f(sc[2]), p3 = exp2f(sc[3]);
                lrun[i] += (p0 + p1) + (p2 + p3);
                half4 pf = {(half_t)p0, (half_t)p1, (half_t)p2, (half_t)p3};
#pragma unroll
                for (int cb = 0; cb < 4; ++cb)
                    accs[i][cb] = __builtin_amdgcn_mfma_f32_16x16x16f16(vf[cb], pf, accs[i][cb], 0, 0, 0);
            }
        }
        if (more) {
#pragma unroll
            for (int p = 0; p < 4; ++p) {
                int idx = p * 256 + tid; int row = idx >> 4, w4 = idx & 15;
                *(u64*)(lds[cur ^ 1] + row * VSTRIDE + w4 * 8) = vn[p];
            }
#pragma unroll
            for (int t = 0; t < 4; ++t) kc[t] = kn[t];
        }
        __syncthreads();
        cur ^= 1;
    }

    float* numb = num + (bz * 2 + br) * 64 * NPIX;
#pragma unroll
    for (int i = 0; i < QF; ++i) {
        float l = lrun[i];
        l += __shfl_xor(l, 16, 64);
        l += __shfl_xor(l, 32, 64);
        int q = qbase + i * 16 + qi;
        if (g == 0) atomicAdd(&lsum[(bz * 2 + br) * NPIX + q], l);
#pragma unroll
        for (int cb = 0; cb < 4; ++cb)
#pragma unroll
            for (int r = 0; r < 4; ++r)
                atomicAdd(&numb[(cb * 16 + 4 * g + r) * NPIX + q], accs[i][cb][r]);
    }
}

// one thread per (bz, c, n4), float4
__global__ __launch_bounds__(256) void norm_kernel(
    const float* __restrict__ num, const float* __restrict__ lsum, float* __restrict__ out)
{
    int tid = blockIdx.x * 256 + threadIdx.x;
    int n4 = tid % 1600;
    int c  = (tid / 1600) & 63;
    int bz = tid / (1600 * 64);
    float4x lA = *(const float4x*)(lsum + (bz * 2 + 0) * NPIX + n4 * 4);
    float4x lC = *(const float4x*)(lsum + (bz * 2 + 1) * NPIX + n4 * 4);
    float4x vA = *(const float4x*)(num + ((bz * 2 + 0) * 64 + c) * NPIX + n4 * 4);
    float4x vC = *(const float4x*)(num + ((bz * 2 + 1) * 64 + c) * NPIX + n4 * 4);
    float4x r;
#pragma unroll
    for (int j = 0; j < 4; ++j)
        r[j] = 0.5f * (vA[j] * __builtin_amdgcn_rcpf(lA[j]) +
                       vC[j] * __builtin_amdgcn_rcpf(lC[j]));
    *(float4x*)(out + (bz * 64 + c) * NPIX + n4 * 4) = r;
}

extern "C" void kernel_launch(void* const* d_in, const int* in_sizes, int n_in,
                              void* d_out, int out_size, void* d_ws, size_t ws_size,
                              hipStream_t stream) {
    (void)in_sizes; (void)n_in; (void)out_size; (void)ws_size;
    const float* a     = (const float*)d_in[0];
    const float* b     = (const float*)d_in[1];
    const float* c     = (const float*)d_in[2];
    const float* wq_ab = (const float*)d_in[3];
    const float* bq_ab = (const float*)d_in[4];
    const float* wk_ab = (const float*)d_in[5];
    const float* bk_ab = (const float*)d_in[6];
    const float* wq_bc = (const float*)d_in[7];
    const float* bq_bc = (const float*)d_in[8];
    const float* wk_bc = (const float*)d_in[9];
    const float* bk_bc = (const float*)d_in[10];
    const float* wv    = (const float*)d_in[11];
    const float* bv    = (const float*)d_in[12];
    float* out = (float*)d_out;

    // workspace: qp | kp | vp | num | lsum
    half_t* qp = (half_t*)d_ws;
    half_t* kp = qp + 2 * 2 * NPIX * 4;
    half_t* vp = kp + 2 * 2 * NPIX * 4;
    float* num  = (float*)(vp + 2 * 64 * NPIX);
    float* lsum = num + 2 * 2 * 64 * NPIX;

    hipMemsetAsync(num, 0, (size_t)(2 * 2 * 64 * NPIX + 2 * 2 * NPIX) * sizeof(float), stream);

    proj_kernel<<<600, 256, 0, stream>>>(a, b, c, wq_ab, bq_ab, wk_ab, bk_ab,
                                         wq_bc, bq_bc, wk_bc, bk_bc, wv, bv, qp, kp, vp);
    attn_kernel<<<1000, 256, 0, stream>>>(qp, kp, vp, num, lsum);
    norm_kernel<<<800, 256, 0, stream>>>(num, lsum, out);
}

// Round 14
// 193.744 us; speedup vs baseline: 1.1370x; 1.0298x over previous
//
#include <hip/hip_runtime.h>
#include <hip/hip_bf16.h>

#define NPIX 6400
#define LOG2E 1.44269504088896340736f
#define KH 5          // split-K ways -> grid 1000
#define KEYS 1280     // keys per split
#define NCH 20        // 64-key chunks per block
#define QF 2          // query fragments (16q each) per wave
#define VSTRIDE 136   // V LDS row stride bytes (34 words: 2-way banks for b64 r/w)

typedef _Float16 half_t;
typedef _Float16 half4 __attribute__((ext_vector_type(4)));
typedef __fp16 fp16x2 __attribute__((ext_vector_type(2)));
typedef float float4x __attribute__((ext_vector_type(4)));
typedef unsigned long long u64;

__device__ __forceinline__ float fast_exp2(float x) {
    float r;
    asm volatile("v_exp_f32 %0, %1" : "=v"(r) : "v"(x));
    return r;
}

// ---------------- fused projections + workspace zeroing ----------------
// blocks 0..399:  v_proj, thread per (bz, c in 0..31, n4); computes c and c+32
// blocks 400..599: qk_proj, thread per (bz, n, d)
// blocks 600..699: zero num+lsum (1664000 floats = 416000 float4)
__global__ __launch_bounds__(256) void proj_kernel(
    const float* __restrict__ a, const float* __restrict__ b, const float* __restrict__ c,
    const float* __restrict__ wq_ab, const float* __restrict__ bq_ab,
    const float* __restrict__ wk_ab, const float* __restrict__ bk_ab,
    const float* __restrict__ wq_bc, const float* __restrict__ bq_bc,
    const float* __restrict__ wk_bc, const float* __restrict__ bk_bc,
    const float* __restrict__ wv, const float* __restrict__ bvb,
    half_t* __restrict__ qp, half_t* __restrict__ kp, half_t* __restrict__ vp,
    float* __restrict__ num)
{
    int bid = blockIdx.x;
    if (bid < 400) {
        int tid = bid * 256 + threadIdx.x;       // 0..102399
        int n4 = tid % 1600;
        int cc = (tid / 1600) & 31;
        int bz = tid / (1600 * 32);
        const float* B = b + bz * 64 * NPIX + n4 * 4;
        float b0 = bvb[cc], b1 = bvb[cc + 32];
        float4x acc0 = {b0, b0, b0, b0}, acc1 = {b1, b1, b1, b1};
        for (int ch = 0; ch < 64; ++ch) {
            float4x bv = *(const float4x*)(B + ch * NPIX);
            acc0 += wv[cc * 64 + ch] * bv;
            acc1 += wv[(cc + 32) * 64 + ch] * bv;
        }
        half4 h0 = {(half_t)acc0[0], (half_t)acc0[1], (half_t)acc0[2], (half_t)acc0[3]};
        half4 h1 = {(half_t)acc1[0], (half_t)acc1[1], (half_t)acc1[2], (half_t)acc1[3]};
        *(half4*)(vp + (bz * 64 + cc) * NPIX + n4 * 4) = h0;
        *(half4*)(vp + (bz * 64 + cc + 32) * NPIX + n4 * 4) = h1;
    } else if (bid < 600) {
        int tid = (bid - 400) * 256 + threadIdx.x;   // 0..51199
        int d = tid & 3;
        int n = (tid >> 2) % NPIX;
        int bz = (tid >> 2) / NPIX;
        const float* A = a + bz * 64 * NPIX + n;
        const float* B = b + bz * 64 * NPIX + n;
        const float* C = c + bz * 64 * NPIX + n;
        float qab = 0.f, kab = 0.f, qbc = 0.f, kbc = 0.f;
#pragma unroll 4
        for (int ch = 0; ch < 64; ++ch) {
            float av = A[ch * NPIX], bv = B[ch * NPIX], cv = C[ch * NPIX];
            qab += wq_ab[d * 64 + ch] * av;
            kab += wk_ab[d * 64 + ch] * bv;
            qbc += wq_bc[d * 64 + ch] * cv;
            kbc += wk_bc[d * 64 + ch] * bv;
        }
        // qp/kp layout: [bz][branch][n][4] fp16; log2e folded into q
        qp[((bz * 2 + 0) * NPIX + n) * 4 + d] = (half_t)((qab + bq_ab[d]) * LOG2E);
        qp[((bz * 2 + 1) * NPIX + n) * 4 + d] = (half_t)((qbc + bq_bc[d]) * LOG2E);
        kp[((bz * 2 + 0) * NPIX + n) * 4 + d] = (half_t)(kab + bk_ab[d]);
        kp[((bz * 2 + 1) * NPIX + n) * 4 + d] = (half_t)(kbc + bk_bc[d]);
    } else {
        int tid = (bid - 600) * 256 + threadIdx.x;   // 0..25599
        float4x z = {0.f, 0.f, 0.f, 0.f};
        float4x* p = (float4x*)num;
        for (int i = tid; i < 416000; i += 25600) p[i] = z;
    }
}

// ---------------- fused attention (flash, no-max softmax, split-K, pipelined) ----
// grid = 1000 (XCD-swizzled): (kh 5) x (bz 2) x (branch 2) x (qchunk 50); 4 waves,
// each wave owns 32 queries (2 fragments). V tile in LDS (136B stride, dbuf).
// Global K/V prefetched one chunk ahead into regs; LDS vf reads double-buffered
// across t. Scores: mfma16x16x16f16(A=K,B=Q) -> S[m=4g+r][q] == PV B-frag layout.
__global__ __launch_bounds__(256) void attn_kernel(
    const half_t* __restrict__ qp, const half_t* __restrict__ kp,
    const half_t* __restrict__ vp, float* __restrict__ num, float* __restrict__ lsum)
{
    int bid = blockIdx.x;
    int swz = (bid & 7) * 125 + (bid >> 3);   // bijective (1000 = 8*125)
    int qc = swz % 50;
    int br = (swz / 50) & 1;
    int bz = (swz / 100) & 1;
    int kh = swz / 200;                        // 0..4

    int tid = threadIdx.x;
    int lane = tid & 63, w = tid >> 6;
    int g = lane >> 4, qi = lane & 15;
    int qbase = qc * 128 + w * 32;

    const half_t* Q = qp + ((bz * 2 + br) * NPIX + qbase) * 4;
    const half_t* K = kp + ((bz * 2 + br) * NPIX + kh * KEYS) * 4;
    const half_t* V = vp + bz * 64 * NPIX + kh * KEYS;

    half4 hz = {(half_t)0, (half_t)0, (half_t)0, (half_t)0};
    half4 qf[QF];
#pragma unroll
    for (int i = 0; i < QF; ++i)
        qf[i] = (lane < 16) ? *(const half4*)(Q + (i * 16 + lane) * 4) : hz;

    float4x accs[QF][4] = {{{0,0,0,0},{0,0,0,0},{0,0,0,0},{0,0,0,0}},
                           {{0,0,0,0},{0,0,0,0},{0,0,0,0},{0,0,0,0}}};
    float lrun[QF] = {0.f, 0.f};

    __shared__ char lds[2][64 * VSTRIDE];

    // prologue: stage chunk 0 (4 b64 slots/thread: idx=p*256+tid -> row=idx>>4, w4=idx&15)
    u64 vpre[4];
#pragma unroll
    for (int p = 0; p < 4; ++p) {
        int idx = p * 256 + tid; int row = idx >> 4, w4 = idx & 15;
        vpre[p] = *(const u64*)(V + row * NPIX + w4 * 4);
    }
    half4 kc[4];
#pragma unroll
    for (int t = 0; t < 4; ++t)
        kc[t] = (lane < 16) ? *(const half4*)(K + (t * 16 + lane) * 4) : hz;
#pragma unroll
    for (int p = 0; p < 4; ++p) {
        int idx = p * 256 + tid; int row = idx >> 4, w4 = idx & 15;
        *(u64*)(lds[0] + row * VSTRIDE + w4 * 8) = vpre[p];
    }
    __syncthreads();

    int cur = 0;
    for (int chn = 0; chn < NCH; ++chn) {
        bool more = (chn + 1 < NCH);
        u64 vn[4];
        half4 kn[4];
        if (more) {   // issue next-chunk global loads early; consumed after compute
            int m0n = (chn + 1) * 64;
#pragma unroll
            for (int p = 0; p < 4; ++p) {
                int idx = p * 256 + tid; int row = idx >> 4, w4 = idx & 15;
                vn[p] = *(const u64*)(V + row * NPIX + m0n + w4 * 4);
            }
#pragma unroll
            for (int t = 0; t < 4; ++t)
                kn[t] = (lane < 16) ? *(const half4*)(K + (m0n + t * 16 + lane) * 4) : hz;
        }
        const char* lb = lds[cur];
        // LDS vf pipeline: prefetch t+1 while computing t
        half4 vfa[4], vfb[4];
#pragma unroll
        for (int cb = 0; cb < 4; ++cb)
            vfa[cb] = *(const half4*)(lb + (cb * 16 + qi) * VSTRIDE + g * 8);
#pragma unroll
        for (int t = 0; t < 4; ++t) {
            half4* vcur = (t & 1) ? vfb : vfa;
            half4* vnxt = (t & 1) ? vfa : vfb;
            if (t < 3) {
#pragma unroll
                for (int cb = 0; cb < 4; ++cb)
                    vnxt[cb] = *(const half4*)(lb + (cb * 16 + qi) * VSTRIDE + (t + 1) * 32 + g * 8);
            }
#pragma unroll
            for (int i = 0; i < QF; ++i) {
                float4x zero = {0.f, 0.f, 0.f, 0.f};
                float4x sc = __builtin_amdgcn_mfma_f32_16x16x16f16(kc[t], qf[i], zero, 0, 0, 0);
                // no-max softmax: |s*log2e| < ~3, exp2 always in range; raw v_exp_f32
                float p0 = fast_exp2(sc[0]), p1 = fast_exp2(sc[1]);
                float p2 = fast_exp2(sc[2]), p3 = fast_exp2(sc[3]);
                lrun[i] += (p0 + p1) + (p2 + p3);
                union { fp16x2 h2[2]; half4 h4; } pk;
                pk.h2[0] = __builtin_amdgcn_cvt_pkrtz(p0, p1);
                pk.h2[1] = __builtin_amdgcn_cvt_pkrtz(p2, p3);
                half4 pf = pk.h4;
#pragma unroll
                for (int cb = 0; cb < 4; ++cb)
                    accs[i][cb] = __builtin_amdgcn_mfma_f32_16x16x16f16(vcur[cb], pf, accs[i][cb], 0, 0, 0);
            }
        }
        if (more) {
#pragma unroll
            for (int p = 0; p < 4; ++p) {
                int idx = p * 256 + tid; int row = idx >> 4, w4 = idx & 15;
                *(u64*)(lds[cur ^ 1] + row * VSTRIDE + w4 * 8) = vn[p];
            }
#pragma unroll
            for (int t = 0; t < 4; ++t) kc[t] = kn[t];
        }
        __syncthreads();
        cur ^= 1;
    }

    float* numb = num + (bz * 2 + br) * 64 * NPIX;
#pragma unroll
    for (int i = 0; i < QF; ++i) {
        float l = lrun[i];
        l += __shfl_xor(l, 16, 64);
        l += __shfl_xor(l, 32, 64);
        int q = qbase + i * 16 + qi;
        if (g == 0) atomicAdd(&lsum[(bz * 2 + br) * NPIX + q], l);
#pragma unroll
        for (int cb = 0; cb < 4; ++cb)
#pragma unroll
            for (int r = 0; r < 4; ++r)
                atomicAdd(&numb[(cb * 16 + 4 * g + r) * NPIX + q], accs[i][cb][r]);
    }
}

// one thread per (bz, c, n4), float4
__global__ __launch_bounds__(256) void norm_kernel(
    const float* __restrict__ num, const float* __restrict__ lsum, float* __restrict__ out)
{
    int tid = blockIdx.x * 256 + threadIdx.x;
    int n4 = tid % 1600;
    int c  = (tid / 1600) & 63;
    int bz = tid / (1600 * 64);
    float4x lA = *(const float4x*)(lsum + (bz * 2 + 0) * NPIX + n4 * 4);
    float4x lC = *(const float4x*)(lsum + (bz * 2 + 1) * NPIX + n4 * 4);
    float4x vA = *(const float4x*)(num + ((bz * 2 + 0) * 64 + c) * NPIX + n4 * 4);
    float4x vC = *(const float4x*)(num + ((bz * 2 + 1) * 64 + c) * NPIX + n4 * 4);
    float4x r;
#pragma unroll
    for (int j = 0; j < 4; ++j)
        r[j] = 0.5f * (vA[j] * __builtin_amdgcn_rcpf(lA[j]) +
                       vC[j] * __builtin_amdgcn_rcpf(lC[j]));
    *(float4x*)(out + (bz * 64 + c) * NPIX + n4 * 4) = r;
}

extern "C" void kernel_launch(void* const* d_in, const int* in_sizes, int n_in,
                              void* d_out, int out_size, void* d_ws, size_t ws_size,
                              hipStream_t stream) {
    (void)in_sizes; (void)n_in; (void)out_size; (void)ws_size;
    const float* a     = (const float*)d_in[0];
    const float* b     = (const float*)d_in[1];
    const float* c     = (const float*)d_in[2];
    const float* wq_ab = (const float*)d_in[3];
    const float* bq_ab = (const float*)d_in[4];
    const float* wk_ab = (const float*)d_in[5];
    const float* bk_ab = (const float*)d_in[6];
    const float* wq_bc = (const float*)d_in[7];
    const float* bq_bc = (const float*)d_in[8];
    const float* wk_bc = (const float*)d_in[9];
    const float* bk_bc = (const float*)d_in[10];
    const float* wv    = (const float*)d_in[11];
    const float* bv    = (const float*)d_in[12];
    float* out = (float*)d_out;

    // workspace: qp | kp | vp | num | lsum  (num+lsum zeroed by proj_kernel)
    half_t* qp = (half_t*)d_ws;
    half_t* kp = qp + 2 * 2 * NPIX * 4;
    half_t* vp = kp + 2 * 2 * NPIX * 4;
    float* num  = (float*)(vp + 2 * 64 * NPIX);
    float* lsum = num + 2 * 2 * 64 * NPIX;

    proj_kernel<<<700, 256, 0, stream>>>(a, b, c, wq_ab, bq_ab, wk_ab, bk_ab,
                                         wq_bc, bq_bc, wk_bc, bk_bc, wv, bv,
                                         qp, kp, vp, num);
    attn_kernel<<<1000, 256, 0, stream>>>(qp, kp, vp, num, lsum);
    norm_kernel<<<800, 256, 0, stream>>>(num, lsum, out);
}